// Round 4
// baseline (136.334 us; speedup 1.0000x reference)
//
#include <hip/hip_runtime.h>

// HardPartPyramidPooling: x(16,256,32,16,11) fp32, labels(16,32,176) int,
// out(16,256,32,16) fp32.  out[n][c][s][p] = sum/cnt + max (0 if cnt==0),
// max floored at NEG_FILL=-100 (reference init).
//
// R9 = R8 block shape (n, even s-pair, 8 channels: every x segment 1408 B
// 128-B aligned; full 128-B out lines) + RANK-SORTED TILE:
//  - bucketing computes each hw position's global sorted position
//    g = base[part] + rank (base via 32-thread prefix scan of cnt),
//    posmap[s'][hw] = g (u8).
//  - tile is scattered into label-sorted row order at store time
//    (12 ds_write_b32 via posmap, read 4 ranks per ds_read_b32).
//  - gather is CONTIGUOUS: thread (p, c, s') reads [base, base+k) from its
//    row with ds_read_b128 (4 elems/instr, no perm unpack, 1 addr add per
//    4 elems).  Gather LDS-instr/wave ~20 -> ~7, VALU ~70 -> ~40.
//  - PITCH=180 floats: rows 16B-aligned (b128 ok); PITCH/4=45 odd -> 16
//    lanes spread over all 8 bank-quads (2-way = free).  perm/BCAP gone.
//  - lgkm-only barriers throughout: x loads stay in flight across the
//    whole bucket/scan/posmap chain (compiler-counted vmcnt at v use).

constexpr int C   = 256;
constexpr int S   = 32;
constexpr int HW  = 176;        // 16*11
constexpr int P   = 16;
constexpr int ROW = S * HW;     // 5632 floats per (n,c)
constexpr int GC  = 8;          // channels per block
constexpr int NS2 = 2;          // s values per block (even base)
constexpr int PITCH = 180;      // floats; %4==0 (b128 align), /4 odd (bank spread)
constexpr float NEG_FILL = -100.0f;

__device__ __forceinline__ void barrier_lgkm() {
    asm volatile("s_waitcnt lgkmcnt(0)\n\ts_barrier" ::: "memory");
}

__global__ __launch_bounds__(256) void hpp_kernel(
    const float* __restrict__ x,
    const int*   __restrict__ labels,
    float*       __restrict__ out)
{
    __shared__ float tile[GC * NS2 * PITCH];                 // 16*180*4 = 11520 B
    __shared__ __align__(4) unsigned char posmap[NS2][HW];   // 352 B
    __shared__ int cnt[NS2 * P];                             // 128 B
    __shared__ int base[NS2 * P];                            // 128 B

    const int tid = threadIdx.x;
    const int blk = blockIdx.x;          // nspair*32 + cg
    const int nsp = blk >> 5, cg = blk & 31;
    const int n   = nsp >> 4, sp = nsp & 15;
    const int s   = sp * 2;              // even

    // ---- labels FIRST (their counted vmcnt wait leaves x loads in flight) --
    const int* ln = labels + (size_t)(n * S + s) * HW;
    int lab0 = 0, lab1 = 0;
    if (tid < HW) { lab0 = ln[tid]; lab1 = ln[HW + tid]; }

    // ---- x loads: 704 float4 = 8 rows(c) x 88; every segment 1408 B,
    //      128-B aligned --------------------------------------------------
    const float* xb = x + (size_t)(n * C + cg * GC) * ROW + s * HW;
    const int f0 = tid, f1 = tid + 256, f2 = tid + 512;
    const int r0 = f0 / 88, j0 = f0 - r0 * 88;
    const int r1 = f1 / 88, j1 = f1 - r1 * 88;
    const int r2 = f2 / 88, j2 = f2 - r2 * 88;
    float4 v0 = *(const float4*)(xb + (size_t)r0 * ROW + j0 * 4);
    float4 v1 = *(const float4*)(xb + (size_t)r1 * ROW + j1 * 4);
    float4 v2 = make_float4(0.f, 0.f, 0.f, 0.f);
    const bool has2 = (f2 < GC * 88);    // 704
    if (has2) v2 = *(const float4*)(xb + (size_t)r2 * ROW + j2 * 4);

    // ---- bucket both rows (all LDS work below hides under x vmcnt) ------
    if (tid < NS2 * P) cnt[tid] = 0;
    barrier_lgkm();
    int a0 = 0, a1 = 0;
    if (tid < HW) {
        a0 = atomicAdd(&cnt[lab0], 1);           // row s   -> set 0
        a1 = atomicAdd(&cnt[P + lab1], 1);       // row s+1 -> set 1
    }
    barrier_lgkm();
    // prefix scan within each set (threads 0..31, <=15 LDS reads each)
    if (tid < NS2 * P) {
        int acc = 0;
        const int b0 = tid & ~(P - 1);
        for (int q = b0; q < tid; ++q) acc += cnt[q];
        base[tid] = acc;
    }
    barrier_lgkm();
    if (tid < HW) {
        posmap[0][tid] = (unsigned char)(base[lab0] + a0);
        posmap[1][tid] = (unsigned char)(base[P + lab1] + a1);
    }
    barrier_lgkm();

    // ---- scatter-store tile into sorted order ---------------------------
    // row c2 = c*2 + s'; element hw -> column posmap[s'][hw]
    {
        const int q0 = j0 * 4, s20 = (q0 >= HW), h0 = q0 - s20 * HW;
        unsigned pm0 = *(const unsigned*)&posmap[s20][h0];   // h0 % 4 == 0
        float* t0 = &tile[(r0 * 2 + s20) * PITCH];
        t0[pm0 & 0xFF] = v0.x; t0[(pm0 >> 8) & 0xFF] = v0.y;
        t0[(pm0 >> 16) & 0xFF] = v0.z; t0[pm0 >> 24] = v0.w;

        const int q1 = j1 * 4, s21 = (q1 >= HW), h1 = q1 - s21 * HW;
        unsigned pm1 = *(const unsigned*)&posmap[s21][h1];
        float* t1 = &tile[(r1 * 2 + s21) * PITCH];
        t1[pm1 & 0xFF] = v1.x; t1[(pm1 >> 8) & 0xFF] = v1.y;
        t1[(pm1 >> 16) & 0xFF] = v1.z; t1[pm1 >> 24] = v1.w;

        if (has2) {
            const int q2 = j2 * 4, s22 = (q2 >= HW), h2 = q2 - s22 * HW;
            unsigned pm2 = *(const unsigned*)&posmap[s22][h2];
            float* t2 = &tile[(r2 * 2 + s22) * PITCH];
            t2[pm2 & 0xFF] = v2.x; t2[(pm2 >> 8) & 0xFF] = v2.y;
            t2[(pm2 >> 16) & 0xFF] = v2.z; t2[pm2 >> 24] = v2.w;
        }
    }
    barrier_lgkm();

    // ---- contiguous gather: p = tid>>4; low = tid&15 -> c = low>>1,
    //      s' = low&1; row = low; range [base, base+k) ---------------------
    const int p   = tid >> 4;
    const int low = tid & 15;
    const int sp2 = low & 1;
    const int c   = low >> 1;
    const int idx = sp2 * P + p;
    const int k   = cnt[idx];
    int off       = base[idx];
    const float* tc = &tile[low * PITCH];

    float s0 = 0.f, s1 = 0.f, m0 = NEG_FILL, m1 = NEG_FILL;
    int rem = k;
    // head: align off to 4
    int h = (4 - (off & 3)) & 3; if (h > rem) h = rem;
    if (h > 0) { float a = tc[off];     s0 += a; m0 = fmaxf(m0, a); }
    if (h > 1) { float a = tc[off + 1]; s1 += a; m1 = fmaxf(m1, a); }
    if (h > 2) { float a = tc[off + 2]; s0 += a; m0 = fmaxf(m0, a); }
    off += h; rem -= h;
    // main: float4 chunks
    int n4 = rem >> 2;
    for (int i = 0; i < n4; ++i) {
        float4 q = *(const float4*)&tc[off];
        s0 += q.x; m0 = fmaxf(m0, q.x);
        s1 += q.y; m1 = fmaxf(m1, q.y);
        s0 += q.z; m0 = fmaxf(m0, q.z);
        s1 += q.w; m1 = fmaxf(m1, q.w);
        off += 4;
    }
    rem &= 3;
    if (rem > 0) { float a = tc[off];     s0 += a; m0 = fmaxf(m0, a); }
    if (rem > 1) { float a = tc[off + 1]; s1 += a; m1 = fmaxf(m1, a); }
    if (rem > 2) { float a = tc[off + 2]; s0 += a; m0 = fmaxf(m0, a); }

    float res = (k > 0) ? (s0 + s1) / (float)k + fmaxf(m0, m1) : 0.f;
    // full 128-B out lines per c: 2 s' x 16 p contiguous
    out[((size_t)(n * C + cg * GC + c) * S + (s + sp2)) * P + p] = res;
}

extern "C" void kernel_launch(void* const* d_in, const int* in_sizes, int n_in,
                              void* d_out, int out_size, void* d_ws, size_t ws_size,
                              hipStream_t stream) {
    const float* x      = (const float*)d_in[0];
    const int*   labels = (const int*)d_in[1];
    float*       out    = (float*)d_out;

    const int ns_total = in_sizes[1] / HW;            // 512
    const int nblk     = (ns_total / NS2) * (C / GC); // 256 * 32 = 8192
    hpp_kernel<<<nblk, 256, 0, stream>>>(x, labels, out);
}